// Round 2
// baseline (298.772 us; speedup 1.0000x reference)
//
#include <hip/hip_runtime.h>
#include <hip/hip_bf16.h>

#define N_NODES 100000
#define N_EDGES 1600000
#define D_IN    128
#define D_HID   16
#define D_OUT   32

#define NBLK_SCAN 391   // ceil(100000/256)

// ---------------------------------------------------------------------------
// CSR build: histogram of dst
// ---------------------------------------------------------------------------
__global__ void k_hist(const int* __restrict__ dst, int* __restrict__ counts) {
    int e = blockIdx.x * blockDim.x + threadIdx.x;
    if (e >= N_EDGES) return;
    atomicAdd(&counts[dst[e]], 1);
}

// Block-level exclusive scan of counts -> offsets (exclusive-in-block), blocksums
__global__ void k_scanA(const int* __restrict__ counts,
                        int* __restrict__ offsets,
                        int* __restrict__ blocksums) {
    __shared__ int s[256];
    int tid = threadIdx.x;
    int idx = blockIdx.x * 256 + tid;
    int v = (idx < N_NODES) ? counts[idx] : 0;
    s[tid] = v;
    __syncthreads();
#pragma unroll
    for (int off = 1; off < 256; off <<= 1) {
        int t = (tid >= off) ? s[tid - off] : 0;
        __syncthreads();
        s[tid] += t;
        __syncthreads();
    }
    if (idx < N_NODES) offsets[idx] = s[tid] - v;   // exclusive within block
    if (tid == 255) blocksums[blockIdx.x] = s[255];
}

// Exclusive scan of the 391 block sums (single block)
__global__ void k_scanB(const int* __restrict__ blocksums,
                        int* __restrict__ blockpfx) {
    __shared__ int s[512];
    int tid = threadIdx.x;
    int v = (tid < NBLK_SCAN) ? blocksums[tid] : 0;
    s[tid] = v;
    __syncthreads();
#pragma unroll
    for (int off = 1; off < 512; off <<= 1) {
        int t = (tid >= off) ? s[tid - off] : 0;
        __syncthreads();
        s[tid] += t;
        __syncthreads();
    }
    if (tid < NBLK_SCAN) blockpfx[tid] = s[tid] - v;
}

// Add block prefix; produce final offsets and the mutable cursor copy
__global__ void k_scanC(int* __restrict__ offsets,
                        const int* __restrict__ blockpfx,
                        int* __restrict__ cursor) {
    int idx = blockIdx.x * 256 + threadIdx.x;
    if (idx < N_NODES) {
        int o = offsets[idx] + blockpfx[blockIdx.x];
        offsets[idx] = o;
        cursor[idx]  = o;
    }
    if (idx == 0) offsets[N_NODES] = N_EDGES;
}

// Scatter edges into dst-grouped order: csr_src[slot] = src[e]
__global__ void k_reorder(const int* __restrict__ src,
                          const int* __restrict__ dst,
                          int* __restrict__ cursor,
                          int* __restrict__ csr_src) {
    int e = blockIdx.x * blockDim.x + threadIdx.x;
    if (e >= N_EDGES) return;
    int d = dst[e];
    int p = atomicAdd(&cursor[d], 1);
    csr_src[p] = src[e];
}

// ---------------------------------------------------------------------------
// Y = feat @ W1  — thread per node, float4 row loads, W1 in LDS (float4 reads)
// ---------------------------------------------------------------------------
__global__ __launch_bounds__(256) void k_mm1(const float* __restrict__ feat,
                                             const float* __restrict__ W1,
                                             float* __restrict__ Y) {
    __shared__ float sW[D_IN * D_HID];  // 8 KB
    for (int i = threadIdx.x; i < D_IN * D_HID; i += 256)
        sW[i] = W1[i];
    __syncthreads();

    int n = blockIdx.x * 256 + threadIdx.x;
    if (n >= N_NODES) return;

    const float4* f4 = (const float4*)(feat + (size_t)n * D_IN);
    const float4* sW4 = (const float4*)sW;   // sW4[k*4 + jq] = W1[k][4jq..4jq+3]

    float4 acc[4];
#pragma unroll
    for (int q = 0; q < 4; ++q) acc[q] = make_float4(0.f, 0.f, 0.f, 0.f);

#pragma unroll 8
    for (int kq = 0; kq < 32; ++kq) {
        float4 f = f4[kq];
        int k0 = kq * 4;
#pragma unroll
        for (int jq = 0; jq < 4; ++jq) {
            float4 w0 = sW4[(k0 + 0) * 4 + jq];
            float4 w1 = sW4[(k0 + 1) * 4 + jq];
            float4 w2 = sW4[(k0 + 2) * 4 + jq];
            float4 w3 = sW4[(k0 + 3) * 4 + jq];
            acc[jq].x += f.x * w0.x + f.y * w1.x + f.z * w2.x + f.w * w3.x;
            acc[jq].y += f.x * w0.y + f.y * w1.y + f.z * w2.y + f.w * w3.y;
            acc[jq].z += f.x * w0.z + f.y * w1.z + f.z * w2.z + f.w * w3.z;
            acc[jq].w += f.x * w0.w + f.y * w1.w + f.z * w2.w + f.w * w3.w;
        }
    }
    float4* y4 = (float4*)(Y + (size_t)n * D_HID);
#pragma unroll
    for (int q = 0; q < 4; ++q) y4[q] = acc[q];
}

// ---------------------------------------------------------------------------
// agg1[n][j] = sum over n's edges of Y[csr_src[i]][j]   (16 lanes per node)
// ---------------------------------------------------------------------------
__global__ void k_agg1(const int* __restrict__ offsets,
                       const int* __restrict__ csr_src,
                       const float* __restrict__ Y,
                       float* __restrict__ agg1) {
    int n = blockIdx.x * 16 + (threadIdx.x >> 4);
    int j = threadIdx.x & 15;
    if (n >= N_NODES) return;
    int beg = offsets[n], end = offsets[n + 1];
    float a = 0.f, b = 0.f;
    int i = beg;
    for (; i + 1 < end; i += 2) {
        int s0 = csr_src[i];
        int s1 = csr_src[i + 1];
        a += Y[(size_t)s0 * D_HID + j];
        b += Y[(size_t)s1 * D_HID + j];
    }
    if (i < end) {
        int s = csr_src[i];
        a += Y[(size_t)s * D_HID + j];
    }
    agg1[(size_t)n * D_HID + j] = a + b;
}

// ---------------------------------------------------------------------------
// agg2[n][j] = sum over edges of relu(agg1[csr_src[i]][j] + b1[j])
// ---------------------------------------------------------------------------
__global__ void k_agg2(const int* __restrict__ offsets,
                       const int* __restrict__ csr_src,
                       const float* __restrict__ agg1,
                       const float* __restrict__ b1,
                       float* __restrict__ agg2) {
    int n = blockIdx.x * 16 + (threadIdx.x >> 4);
    int j = threadIdx.x & 15;
    if (n >= N_NODES) return;
    float bj = b1[j];
    int beg = offsets[n], end = offsets[n + 1];
    float a = 0.f, b = 0.f;
    int i = beg;
    for (; i + 1 < end; i += 2) {
        int s0 = csr_src[i];
        int s1 = csr_src[i + 1];
        float h0 = agg1[(size_t)s0 * D_HID + j] + bj;
        float h1 = agg1[(size_t)s1 * D_HID + j] + bj;
        a += h0 > 0.f ? h0 : 0.f;
        b += h1 > 0.f ? h1 : 0.f;
    }
    if (i < end) {
        int s = csr_src[i];
        float h = agg1[(size_t)s * D_HID + j] + bj;
        a += h > 0.f ? h : 0.f;
    }
    agg2[(size_t)n * D_HID + j] = a + b;
}

// ---------------------------------------------------------------------------
// out = agg2 @ W2 + b2
// ---------------------------------------------------------------------------
__global__ void k_mm2(const float* __restrict__ agg2,
                      const float* __restrict__ W2,
                      const float* __restrict__ b2,
                      float* __restrict__ out) {
    int gid = blockIdx.x * blockDim.x + threadIdx.x;
    if (gid >= N_NODES * D_OUT) return;
    int n = gid >> 5;
    int o = gid & 31;
    const float* arow = agg2 + (size_t)n * D_HID;
    float acc = b2[o];
#pragma unroll
    for (int j = 0; j < D_HID; ++j)
        acc = fmaf(arow[j], W2[j * D_OUT + o], acc);
    out[gid] = acc;
}

// ---------------------------------------------------------------------------
extern "C" void kernel_launch(void* const* d_in, const int* in_sizes, int n_in,
                              void* d_out, int out_size, void* d_ws, size_t ws_size,
                              hipStream_t stream) {
    const float* feat = (const float*)d_in[0];
    const int*   src  = (const int*)d_in[1];
    const int*   dst  = (const int*)d_in[2];
    const float* W1   = (const float*)d_in[3];
    const float* b1   = (const float*)d_in[4];
    const float* W2   = (const float*)d_in[5];
    const float* b2   = (const float*)d_in[6];
    float* out = (float*)d_out;

    // ws layout (proven 19.2 MB footprint from round 1):
    //   [0      , 6.4M)  csr_src   (int, 1.6M)
    //   [6.4M   , 12.8M) Y  -> later reused as agg2
    //   [12.8M  , 19.2M) agg1; before agg1 is written this region hosts:
    //       counts    @ 12.8M  (400 KB)
    //       cursor    @ 13.2M  (400 KB)
    //       blocksums @ 13.6M  (391*4 B)
    //       blockpfx  @ 13.7M  (391*4 B)
    char* base = (char*)d_ws;
    const size_t SZ = (size_t)N_NODES * D_HID * sizeof(float);  // 6,400,000
    int*   csr_src = (int*)(base);
    float* Y       = (float*)(base + SZ);
    float* agg2    = Y;                       // alias: Y dead after k_agg1
    float* agg1    = (float*)(base + 2 * SZ);
    int*   counts    = (int*)(base + 2 * SZ);
    int*   cursor    = (int*)(base + 2 * SZ + 400 * 1024);
    int*   blocksums = (int*)(base + 2 * SZ + 800 * 1024);
    int*   blockpfx  = (int*)(base + 2 * SZ + 900 * 1024);

    // offsets (100001 ints = 400,004 B) lives in the tail of d_out; d_out is
    // fully overwritten by k_mm2 afterwards, and offsets is dead by then.
    int* offsets = (int*)((char*)d_out +
                          (size_t)N_NODES * D_OUT * sizeof(float) - 400004);

    hipMemsetAsync(counts, 0, (size_t)N_NODES * sizeof(int), stream);

    // --- CSR build ---
    k_hist   <<<N_EDGES / 256, 256, 0, stream>>>(dst, counts);
    k_scanA  <<<NBLK_SCAN, 256, 0, stream>>>(counts, offsets, blocksums);
    k_scanB  <<<1, 512, 0, stream>>>(blocksums, blockpfx);
    k_scanC  <<<NBLK_SCAN, 256, 0, stream>>>(offsets, blockpfx, cursor);
    k_reorder<<<N_EDGES / 256, 256, 0, stream>>>(src, dst, cursor, csr_src);

    // --- layer 1 projection (cheap order: project then aggregate) ---
    k_mm1<<<(N_NODES + 255) / 256, 256, 0, stream>>>(feat, W1, Y);

    // --- aggregations as gathers (no fp atomics) ---
    k_agg1<<<(N_NODES + 15) / 16, 256, 0, stream>>>(offsets, csr_src, Y, agg1);
    k_agg2<<<(N_NODES + 15) / 16, 256, 0, stream>>>(offsets, csr_src, agg1, b1, agg2);

    // --- layer 2 projection ---
    k_mm2<<<(N_NODES * D_OUT + 255) / 256, 256, 0, stream>>>(agg2, W2, b2, out);
}